// Round 1
// baseline (2352.833 us; speedup 1.0000x reference)
//
#include <hip/hip_runtime.h>
#include <hip/hip_bf16.h>

#define BB 2
#define SS 2048
#define DD 512
#define HH 8
#define DP 64
#define MR 1024
#define BSD (BB * SS * DD)

constexpr float kNegInf = -1.0e9f;
constexpr float kScale  = 0.125f;   // 1/sqrt(64)

// ---------------------------------------------------------------------------
// GEMM: C[m][n] = sum_k X[m][k] * W[n][k] + bias[n]   (i.e. X @ W^T + b)
// M = 4096, N = 512, K = 512 fixed. Grid (64, 8), block 256.
// 64x64 tile, 4x4 per thread, K-step 16, LDS stride 20 (2-way-free banks,
// 80B rows keep float4 alignment).
// ---------------------------------------------------------------------------
__global__ __launch_bounds__(256) void gemm_xwT_512(
    const float* __restrict__ X, const float* __restrict__ W,
    const float* __restrict__ bias, float* __restrict__ C)
{
    __shared__ float Xs[64][20];
    __shared__ float Ws[64][20];
    const int t  = threadIdx.x;
    const int tx = t & 15, ty = t >> 4;
    const int lr = t >> 2, lc = t & 3;
    const int m0 = blockIdx.x * 64, n0 = blockIdx.y * 64;
    float acc[4][4] = {};
    for (int k0 = 0; k0 < 512; k0 += 16) {
        float4 xv = *(const float4*)(X + (size_t)(m0 + lr) * 512 + k0 + lc * 4);
        float4 wv = *(const float4*)(W + (size_t)(n0 + lr) * 512 + k0 + lc * 4);
        *(float4*)&Xs[lr][lc * 4] = xv;
        *(float4*)&Ws[lr][lc * 4] = wv;
        __syncthreads();
#pragma unroll
        for (int kk = 0; kk < 16; kk += 4) {
            float4 a[4], b[4];
#pragma unroll
            for (int ii = 0; ii < 4; ii++) a[ii] = *(const float4*)&Xs[ty * 4 + ii][kk];
#pragma unroll
            for (int jj = 0; jj < 4; jj++) b[jj] = *(const float4*)&Ws[tx + 16 * jj][kk];
#pragma unroll
            for (int ii = 0; ii < 4; ii++)
#pragma unroll
                for (int jj = 0; jj < 4; jj++)
                    acc[ii][jj] += a[ii].x * b[jj].x + a[ii].y * b[jj].y +
                                   a[ii].z * b[jj].z + a[ii].w * b[jj].w;
        }
        __syncthreads();
    }
#pragma unroll
    for (int ii = 0; ii < 4; ii++) {
        const size_t m = (size_t)(m0 + ty * 4 + ii);
#pragma unroll
        for (int jj = 0; jj < 4; jj++) {
            const int n = n0 + tx + 16 * jj;
            C[m * 512 + n] = acc[ii][jj] + bias[n];
        }
    }
}

// ---------------------------------------------------------------------------
// Relative logits: G[bh][i][t] = sum_d qp[b][i][h*64+d] * E[t][h*64+d]  (bf16)
// Grid (2048/64, 1024/64, 16), block 256.
// ---------------------------------------------------------------------------
__global__ __launch_bounds__(256) void relg_kernel(
    const float* __restrict__ qp, const float* __restrict__ E,
    __hip_bfloat16* __restrict__ G)
{
    __shared__ float As[64][20];
    __shared__ float Bs[64][20];
    const int t  = threadIdx.x;
    const int tx = t & 15, ty = t >> 4;
    const int lr = t >> 2, lc = t & 3;
    const int bh = blockIdx.z;
    const int b = bh >> 3, h = bh & 7;
    const int i0 = blockIdx.x * 64, t0 = blockIdx.y * 64;
    const float* A  = qp + (size_t)b * SS * DD + h * DP;
    const float* Bm = E + h * DP;
    float acc[4][4] = {};
    for (int k0 = 0; k0 < DP; k0 += 16) {
        float4 xv = *(const float4*)(A  + (size_t)(i0 + lr) * DD + k0 + lc * 4);
        float4 wv = *(const float4*)(Bm + (size_t)(t0 + lr) * DD + k0 + lc * 4);
        *(float4*)&As[lr][lc * 4] = xv;
        *(float4*)&Bs[lr][lc * 4] = wv;
        __syncthreads();
#pragma unroll
        for (int kk = 0; kk < 16; kk += 4) {
            float4 a[4], b4[4];
#pragma unroll
            for (int ii = 0; ii < 4; ii++) a[ii]  = *(const float4*)&As[ty * 4 + ii][kk];
#pragma unroll
            for (int jj = 0; jj < 4; jj++) b4[jj] = *(const float4*)&Bs[tx + 16 * jj][kk];
#pragma unroll
            for (int ii = 0; ii < 4; ii++)
#pragma unroll
                for (int jj = 0; jj < 4; jj++)
                    acc[ii][jj] += a[ii].x * b4[jj].x + a[ii].y * b4[jj].y +
                                   a[ii].z * b4[jj].z + a[ii].w * b4[jj].w;
        }
        __syncthreads();
    }
#pragma unroll
    for (int ii = 0; ii < 4; ii++) {
        const size_t i = (size_t)(i0 + ty * 4 + ii);
#pragma unroll
        for (int jj = 0; jj < 4; jj++) {
            const int tt = t0 + tx + 16 * jj;
            G[((size_t)bh * SS + i) * MR + tt] = __float2bfloat16(acc[ii][jj]);
        }
    }
}

// ---------------------------------------------------------------------------
// Flash attention with skewed relative logits folded in as G-table lookups.
// Grid (2048/64, 16), block 256. One workgroup = one (bh, 64-row Q tile).
// LDS: qs(65x68) + kst(64x68, K tile then scores) + vsT(64x68) ~ 54.5 KB.
// ---------------------------------------------------------------------------
__global__ __launch_bounds__(256) void attn_kernel(
    const float* __restrict__ qp, const float* __restrict__ kp,
    const float* __restrict__ vp, const int* __restrict__ mask,
    const __hip_bfloat16* __restrict__ G, float* __restrict__ ao)
{
    __shared__ float qs[65][68];
    __shared__ float kst[64][68];   // K tile during QK, then scores/probs
    __shared__ float vsT[64][68];   // V tile transposed: [d][j]
    __shared__ float red[64][4];
    __shared__ float mrow[64], lrow[64], arow[64];
    __shared__ float d0s[65];

    const int t  = threadIdx.x;
    const int tx = t & 15, ty = t >> 4;
    const int bh = blockIdx.y;
    const int b  = bh >> 3, h = bh & 7;
    const int q0 = blockIdx.x * 64;

    const float* qbase = qp + (size_t)b * SS * DD + h * DP;
    const float* kbase = kp + (size_t)b * SS * DD + h * DP;
    const float* vbase = vp + (size_t)b * SS * DD + h * DP;
    const __hip_bfloat16* Gb = G + (size_t)bh * SS * MR;
    const int* mbase = mask + (size_t)b * SS * SS;

    // ---- stage Q tile (64 rows + the i+1 spill row) ----
#pragma unroll
    for (int rr = 0; rr < 4; rr++) {
        const int row = (t >> 4) + 16 * rr;
        *(float4*)&qs[row][tx * 4] =
            *(const float4*)(qbase + (size_t)(q0 + row) * DD + tx * 4);
    }
    if (t < 16) {
        float4 v4 = make_float4(0.f, 0.f, 0.f, 0.f);
        if (q0 + 64 < SS) v4 = *(const float4*)(qbase + (size_t)(q0 + 64) * DD + t * 4);
        *(float4*)&qs[64][t * 4] = v4;
    }
    if (t < 65) {
        d0s[t] = (q0 + t < SS) ? __bfloat162float(Gb[(size_t)(q0 + t) * MR]) : 0.0f;
    }
    if (t < 64) { mrow[t] = -3.0e38f; lrow[t] = 0.0f; }

    float o[4][4] = {};

    for (int k0 = 0; k0 < SS; k0 += 64) {
        __syncthreads();   // protects init phase / previous iteration's reads
        // ---- stage K tile and V^T tile ----
#pragma unroll
        for (int rr = 0; rr < 4; rr++) {
            const int row = (t >> 4) + 16 * rr;
            *(float4*)&kst[row][tx * 4] =
                *(const float4*)(kbase + (size_t)(k0 + row) * DD + tx * 4);
            float4 vv = *(const float4*)(vbase + (size_t)(k0 + row) * DD + tx * 4);
            vsT[tx * 4 + 0][row] = vv.x;
            vsT[tx * 4 + 1][row] = vv.y;
            vsT[tx * 4 + 2][row] = vv.z;
            vsT[tx * 4 + 3][row] = vv.w;
        }
        __syncthreads();

        // ---- QK^T (4x4 per thread, float4 over depth) ----
        float acc[4][4] = {};
#pragma unroll
        for (int kk = 0; kk < DP; kk += 4) {
            float4 a[4], bv[4];
#pragma unroll
            for (int ii = 0; ii < 4; ii++) a[ii]  = *(const float4*)&qs[ty * 4 + ii][kk];
#pragma unroll
            for (int jj = 0; jj < 4; jj++) bv[jj] = *(const float4*)&kst[tx + 16 * jj][kk];
#pragma unroll
            for (int ii = 0; ii < 4; ii++)
#pragma unroll
                for (int jj = 0; jj < 4; jj++)
                    acc[ii][jj] += a[ii].x * bv[jj].x + a[ii].y * bv[jj].y +
                                   a[ii].z * bv[jj].z + a[ii].w * bv[jj].w;
        }
        __syncthreads();   // finish all kst reads before overwriting with scores

        // ---- relative logits (skew via G lookups) + mask + scale ----
#pragma unroll
        for (int ii = 0; ii < 4; ii++) {
            const int i  = ty * 4 + ii;
            const int gi = q0 + i;
#pragma unroll
            for (int jj = 0; jj < 4; jj++) {
                const int j  = tx + 16 * jj;
                const int gj = k0 + j;
                const int dd = gi - gj;
                float rel;
                if (dd >= MR)             rel = d0s[i];
                else if (dd >= 0)         rel = __bfloat162float(Gb[(size_t)gi * MR + (MR - 1 - dd)]);
                else if (dd == -1)        rel = 0.0f;
                else if (dd >= -(MR + 1)) rel = d0s[i + 1];
                else                      rel = __bfloat162float(Gb[(size_t)(gi + 1) * MR + (-dd - (MR + 2))]);
                const int mv = mbase[(size_t)gi * SS + gj];
                kst[i][j] = (acc[ii][jj] + rel) * kScale + (float)mv * kNegInf;
            }
        }
        __syncthreads();

        // ---- row max (4 threads per row) ----
        {
            const int r = t >> 2, sg = t & 3;
            float pm = -3.0e38f;
#pragma unroll
            for (int c = 0; c < 16; c++) pm = fmaxf(pm, kst[r][sg * 16 + c]);
            red[r][sg] = pm;
        }
        __syncthreads();
        if (t < 64) {
            float tm   = fmaxf(fmaxf(red[t][0], red[t][1]), fmaxf(red[t][2], red[t][3]));
            float mnew = fmaxf(mrow[t], tm);
            arow[t] = __expf(mrow[t] - mnew);
            mrow[t] = mnew;
        }
        __syncthreads();
        // ---- exponentiate + partial row sums ----
        {
            const int r = t >> 2, sg = t & 3;
            const float mr = mrow[r];
            float ps = 0.0f;
#pragma unroll
            for (int c = 0; c < 16; c++) {
                float p = __expf(kst[r][sg * 16 + c] - mr);
                kst[r][sg * 16 + c] = p;
                ps += p;
            }
            red[r][sg] = ps;
        }
        __syncthreads();
        if (t < 64) {
            lrow[t] = lrow[t] * arow[t] + red[t][0] + red[t][1] + red[t][2] + red[t][3];
        }
        // ---- PV: o = o*alpha + P @ V (float4 over j via transposed V) ----
#pragma unroll
        for (int ii = 0; ii < 4; ii++) {
            const float al = arow[ty * 4 + ii];
#pragma unroll
            for (int jj = 0; jj < 4; jj++) o[ii][jj] *= al;
        }
#pragma unroll
        for (int js = 0; js < 64; js += 4) {
            float4 p4[4], v4[4];
#pragma unroll
            for (int ii = 0; ii < 4; ii++) p4[ii] = *(const float4*)&kst[ty * 4 + ii][js];
#pragma unroll
            for (int jj = 0; jj < 4; jj++) v4[jj] = *(const float4*)&vsT[tx + 16 * jj][js];
#pragma unroll
            for (int ii = 0; ii < 4; ii++)
#pragma unroll
                for (int jj = 0; jj < 4; jj++)
                    o[ii][jj] += p4[ii].x * v4[jj].x + p4[ii].y * v4[jj].y +
                                 p4[ii].z * v4[jj].z + p4[ii].w * v4[jj].w;
        }
    }
    __syncthreads();
    // ---- normalize and write merged-head attention output ----
#pragma unroll
    for (int ii = 0; ii < 4; ii++) {
        const int i = ty * 4 + ii;
        const float inv = 1.0f / lrow[i];
#pragma unroll
        for (int jj = 0; jj < 4; jj++) {
            ao[(size_t)b * SS * DD + (size_t)(q0 + i) * DD + h * DP + tx + 16 * jj] =
                o[ii][jj] * inv;
        }
    }
}

// ---------------------------------------------------------------------------
extern "C" void kernel_launch(void* const* d_in, const int* in_sizes, int n_in,
                              void* d_out, int out_size, void* d_ws, size_t ws_size,
                              hipStream_t stream)
{
    const float* q    = (const float*)d_in[0];
    const float* k    = (const float*)d_in[1];
    const float* v    = (const float*)d_in[2];
    const int*   mask = (const int*)d_in[3];
    const float* Wq_w = (const float*)d_in[4];
    const float* Wq_b = (const float*)d_in[5];
    const float* Wk_w = (const float*)d_in[6];
    const float* Wk_b = (const float*)d_in[7];
    const float* Wv_w = (const float*)d_in[8];
    const float* Wv_b = (const float*)d_in[9];
    const float* E    = (const float*)d_in[10];
    const float* Wo_w = (const float*)d_in[11];
    const float* Wo_b = (const float*)d_in[12];
    float* out = (float*)d_out;

    // workspace layout (96 MiB): qp | kp | vp | ao (fp32) | G (bf16)
    float* qp = (float*)d_ws;
    float* kp = qp + BSD;
    float* vp = kp + BSD;
    float* ao = vp + BSD;
    __hip_bfloat16* G = (__hip_bfloat16*)(ao + BSD);

    dim3 blk(256);
    dim3 pg(4096 / 64, 512 / 64);
    hipLaunchKernelGGL(gemm_xwT_512, pg, blk, 0, stream, q, Wq_w, Wq_b, qp);
    hipLaunchKernelGGL(gemm_xwT_512, pg, blk, 0, stream, k, Wk_w, Wk_b, kp);
    hipLaunchKernelGGL(gemm_xwT_512, pg, blk, 0, stream, v, Wv_w, Wv_b, vp);
    hipLaunchKernelGGL(relg_kernel, dim3(SS / 64, MR / 64, 16), blk, 0, stream, qp, E, G);
    hipLaunchKernelGGL(attn_kernel, dim3(SS / 64, 16), blk, 0, stream, qp, kp, vp, mask, G, ao);
    hipLaunchKernelGGL(gemm_xwT_512, pg, blk, 0, stream, ao, Wo_w, Wo_b, out);
}

// Round 2
// 520.071 us; speedup vs baseline: 4.5241x; 4.5241x over previous
//
#include <hip/hip_runtime.h>
#include <hip/hip_bf16.h>

#define BB 2
#define SS 2048
#define DD 512
#define HH 8
#define DP 64
#define MR 1024
#define BSD (BB * SS * DD)

constexpr float kNegInf = -1.0e9f;
constexpr float kScale  = 0.125f;   // 1/sqrt(64)

typedef __attribute__((ext_vector_type(8))) short bf16x8;
typedef __attribute__((ext_vector_type(4))) float floatx4;

static __device__ __forceinline__ unsigned short f2b(float x) {
    __hip_bfloat16 h = __float2bfloat16(x);
    return *reinterpret_cast<unsigned short*>(&h);
}

// ---------------------------------------------------------------------------
// GEMM: C[m][n] = sum_k X[m][k] * W[n][k] + bias[n]   (i.e. X @ W^T + b)
// M = 4096, N = 512, K = 512 fixed. Grid (64, 8), block 256.
// ---------------------------------------------------------------------------
__global__ __launch_bounds__(256) void gemm_xwT_512(
    const float* __restrict__ X, const float* __restrict__ W,
    const float* __restrict__ bias, float* __restrict__ C)
{
    __shared__ float Xs[64][20];
    __shared__ float Ws[64][20];
    const int t  = threadIdx.x;
    const int tx = t & 15, ty = t >> 4;
    const int lr = t >> 2, lc = t & 3;
    const int m0 = blockIdx.x * 64, n0 = blockIdx.y * 64;
    float acc[4][4] = {};
    for (int k0 = 0; k0 < 512; k0 += 16) {
        float4 xv = *(const float4*)(X + (size_t)(m0 + lr) * 512 + k0 + lc * 4);
        float4 wv = *(const float4*)(W + (size_t)(n0 + lr) * 512 + k0 + lc * 4);
        *(float4*)&Xs[lr][lc * 4] = xv;
        *(float4*)&Ws[lr][lc * 4] = wv;
        __syncthreads();
#pragma unroll
        for (int kk = 0; kk < 16; kk += 4) {
            float4 a[4], b[4];
#pragma unroll
            for (int ii = 0; ii < 4; ii++) a[ii] = *(const float4*)&Xs[ty * 4 + ii][kk];
#pragma unroll
            for (int jj = 0; jj < 4; jj++) b[jj] = *(const float4*)&Ws[tx + 16 * jj][kk];
#pragma unroll
            for (int ii = 0; ii < 4; ii++)
#pragma unroll
                for (int jj = 0; jj < 4; jj++)
                    acc[ii][jj] += a[ii].x * b[jj].x + a[ii].y * b[jj].y +
                                   a[ii].z * b[jj].z + a[ii].w * b[jj].w;
        }
        __syncthreads();
    }
#pragma unroll
    for (int ii = 0; ii < 4; ii++) {
        const size_t m = (size_t)(m0 + ty * 4 + ii);
#pragma unroll
        for (int jj = 0; jj < 4; jj++) {
            const int n = n0 + tx + 16 * jj;
            C[m * 512 + n] = acc[ii][jj] + bias[n];
        }
    }
}

// ---------------------------------------------------------------------------
// Relative logits: G[bh][i][t] = sum_d qp[b][i][h*64+d] * E[t][h*64+d]  (bf16)
// Grid (2048/64, 1024/64, 16), block 256.
// ---------------------------------------------------------------------------
__global__ __launch_bounds__(256) void relg_kernel(
    const float* __restrict__ qp, const float* __restrict__ E,
    __hip_bfloat16* __restrict__ G)
{
    __shared__ float As[64][20];
    __shared__ float Bs[64][20];
    const int t  = threadIdx.x;
    const int tx = t & 15, ty = t >> 4;
    const int lr = t >> 2, lc = t & 3;
    const int bh = blockIdx.z;
    const int b = bh >> 3, h = bh & 7;
    const int i0 = blockIdx.x * 64, t0 = blockIdx.y * 64;
    const float* A  = qp + (size_t)b * SS * DD + h * DP;
    const float* Bm = E + h * DP;
    float acc[4][4] = {};
    for (int k0 = 0; k0 < DP; k0 += 16) {
        float4 xv = *(const float4*)(A  + (size_t)(i0 + lr) * DD + k0 + lc * 4);
        float4 wv = *(const float4*)(Bm + (size_t)(t0 + lr) * DD + k0 + lc * 4);
        *(float4*)&As[lr][lc * 4] = xv;
        *(float4*)&Bs[lr][lc * 4] = wv;
        __syncthreads();
#pragma unroll
        for (int kk = 0; kk < 16; kk += 4) {
            float4 a[4], b4[4];
#pragma unroll
            for (int ii = 0; ii < 4; ii++) a[ii]  = *(const float4*)&As[ty * 4 + ii][kk];
#pragma unroll
            for (int jj = 0; jj < 4; jj++) b4[jj] = *(const float4*)&Bs[tx + 16 * jj][kk];
#pragma unroll
            for (int ii = 0; ii < 4; ii++)
#pragma unroll
                for (int jj = 0; jj < 4; jj++)
                    acc[ii][jj] += a[ii].x * b4[jj].x + a[ii].y * b4[jj].y +
                                   a[ii].z * b4[jj].z + a[ii].w * b4[jj].w;
        }
        __syncthreads();
    }
#pragma unroll
    for (int ii = 0; ii < 4; ii++) {
        const size_t i = (size_t)(i0 + ty * 4 + ii);
#pragma unroll
        for (int jj = 0; jj < 4; jj++) {
            const int tt = t0 + tx + 16 * jj;
            G[((size_t)bh * SS + i) * MR + tt] = __float2bfloat16(acc[ii][jj]);
        }
    }
}

// ---------------------------------------------------------------------------
// Flash attention, bf16 MFMA (16x16x32). One block = one (bh, 64-row Q tile),
// 4 waves, each wave owns 16 Q rows. K staged natural, V staged transposed,
// P round-trips C-layout -> A-layout through a wave-private LDS strip.
// Skewed relative logits folded in via a single branch-free clamped G lookup.
// Grid (16 bh, 32 qtiles), block 256. LDS = 3 * 64*72*2B = 27.6 KB.
// ---------------------------------------------------------------------------
#define P2 72

__global__ __launch_bounds__(256) void attn_kernel(
    const float* __restrict__ qp, const float* __restrict__ kp,
    const float* __restrict__ vp, const int* __restrict__ mask,
    const __hip_bfloat16* __restrict__ G, float* __restrict__ ao)
{
    __shared__ unsigned short Ks[64 * P2];
    __shared__ unsigned short Vt[64 * P2];   // V transposed: [depth][key]
    __shared__ unsigned short Ps[64 * P2];   // Q staging, then per-wave P strips

    const int t    = threadIdx.x;
    const int w    = t >> 6;
    const int lane = t & 63;
    const int quad = lane >> 4;
    const int l15  = lane & 15;
    const int bh   = blockIdx.x;
    const int q0   = blockIdx.y * 64;
    const int b    = bh >> 3, h = bh & 7;

    const float* qbase = qp + (size_t)b * SS * DD + h * DP;
    const float* kbase = kp + (size_t)b * SS * DD + h * DP;
    const float* vbase = vp + (size_t)b * SS * DD + h * DP;
    const __hip_bfloat16* Gb = G + (size_t)bh * SS * MR;
    const int* mbase = mask + (size_t)b * SS * SS;

    // ---- stage Q tile -> Ps (bf16) ----
#pragma unroll
    for (int p = 0; p < 4; p++) {
        const int idx = t + 256 * p;
        const int row = idx >> 4, c4 = (idx & 15) * 4;
        float4 qv = *(const float4*)(qbase + (size_t)(q0 + row) * DD + c4);
        ushort4 u;
        u.x = f2b(qv.x); u.y = f2b(qv.y); u.z = f2b(qv.z); u.w = f2b(qv.w);
        *(ushort4*)&Ps[row * P2 + c4] = u;
    }
    __syncthreads();

    // ---- Q A-fragments, resident for the whole k-loop ----
    bf16x8 qf[2];
    qf[0] = *(const bf16x8*)&Ps[(w * 16 + l15) * P2 + 0  + quad * 8];
    qf[1] = *(const bf16x8*)&Ps[(w * 16 + l15) * P2 + 32 + quad * 8];

    floatx4 oacc[4];
#pragma unroll
    for (int ct = 0; ct < 4; ct++) oacc[ct] = (floatx4){0.f, 0.f, 0.f, 0.f};
    float mrow[4] = {-3.0e38f, -3.0e38f, -3.0e38f, -3.0e38f};
    float lrow[4] = {0.f, 0.f, 0.f, 0.f};

    for (int k0 = 0; k0 < SS; k0 += 64) {
        __syncthreads();   // prior iteration's Ks/Vt reads (and Q frag reads) done
        // ---- stage K tile (natural) and V tile (transposed), fp32 -> bf16 ----
#pragma unroll
        for (int p = 0; p < 4; p++) {
            const int idx = t + 256 * p;
            const int row = idx >> 4, c4 = (idx & 15) * 4;
            float4 kv = *(const float4*)(kbase + (size_t)(k0 + row) * DD + c4);
            ushort4 u;
            u.x = f2b(kv.x); u.y = f2b(kv.y); u.z = f2b(kv.z); u.w = f2b(kv.w);
            *(ushort4*)&Ks[row * P2 + c4] = u;
            float4 vv = *(const float4*)(vbase + (size_t)(k0 + row) * DD + c4);
            Vt[(c4 + 0) * P2 + row] = f2b(vv.x);
            Vt[(c4 + 1) * P2 + row] = f2b(vv.y);
            Vt[(c4 + 2) * P2 + row] = f2b(vv.z);
            Vt[(c4 + 3) * P2 + row] = f2b(vv.w);
        }
        __syncthreads();

        // ---- relative-logit + mask bias (hoisted loads overlap the MFMAs) ----
        float ext[4][4];
#pragma unroll
        for (int ct = 0; ct < 4; ct++) {
            const int gj = k0 + ct * 16 + l15;
#pragma unroll
            for (int r = 0; r < 4; r++) {
                const int gi = q0 + w * 16 + quad * 4 + r;
                const int dd = gi - gj;
                const int grow = (dd < 0) ? min(gi + 1, SS - 1) : gi;
                const int gidx = (dd < 0) ? max(-dd - (MR + 2), 0) : max(MR - 1 - dd, 0);
                float rel = __bfloat162float(Gb[(size_t)grow * MR + gidx]);
                if (dd == -1) rel = 0.0f;
                const int mv = mbase[(size_t)gi * SS + gj];
                ext[ct][r] = rel * kScale + (float)mv * kNegInf;
            }
        }

        // ---- QK^T MFMAs ----
        floatx4 acc[4];
#pragma unroll
        for (int ct = 0; ct < 4; ct++) acc[ct] = (floatx4){0.f, 0.f, 0.f, 0.f};
#pragma unroll
        for (int ks = 0; ks < 2; ks++) {
#pragma unroll
            for (int ct = 0; ct < 4; ct++) {
                bf16x8 bf = *(const bf16x8*)&Ks[(ct * 16 + l15) * P2 + ks * 32 + quad * 8];
                acc[ct] = __builtin_amdgcn_mfma_f32_16x16x32_bf16(qf[ks], bf, acc[ct], 0, 0, 0);
            }
        }

        // ---- online softmax (rows live in 16-lane groups; shfl_xor reduce) ----
        float pmat[4][4];
        float alpha[4];
#pragma unroll
        for (int r = 0; r < 4; r++) {
            float s0 = acc[0][r] * kScale + ext[0][r];
            float s1 = acc[1][r] * kScale + ext[1][r];
            float s2 = acc[2][r] * kScale + ext[2][r];
            float s3 = acc[3][r] * kScale + ext[3][r];
            float mx = fmaxf(fmaxf(s0, s1), fmaxf(s2, s3));
            mx = fmaxf(mx, __shfl_xor(mx, 1));
            mx = fmaxf(mx, __shfl_xor(mx, 2));
            mx = fmaxf(mx, __shfl_xor(mx, 4));
            mx = fmaxf(mx, __shfl_xor(mx, 8));
            const float mnew = fmaxf(mrow[r], mx);
            alpha[r] = __expf(mrow[r] - mnew);
            mrow[r] = mnew;
            float p0 = __expf(s0 - mnew);
            float p1 = __expf(s1 - mnew);
            float p2 = __expf(s2 - mnew);
            float p3 = __expf(s3 - mnew);
            pmat[0][r] = p0; pmat[1][r] = p1; pmat[2][r] = p2; pmat[3][r] = p3;
            float ps = p0 + p1 + p2 + p3;
            ps += __shfl_xor(ps, 1);
            ps += __shfl_xor(ps, 2);
            ps += __shfl_xor(ps, 4);
            ps += __shfl_xor(ps, 8);
            lrow[r] = lrow[r] * alpha[r] + ps;
        }

        // ---- write P strip (wave-private rows; in-wave lgkm ordering only) ----
#pragma unroll
        for (int ct = 0; ct < 4; ct++)
#pragma unroll
            for (int r = 0; r < 4; r++)
                Ps[(w * 16 + quad * 4 + r) * P2 + ct * 16 + l15] = f2b(pmat[ct][r]);

        // ---- rescale O ----
#pragma unroll
        for (int ct = 0; ct < 4; ct++)
#pragma unroll
            for (int r = 0; r < 4; r++)
                oacc[ct][r] *= alpha[r];

        // ---- PV MFMAs ----
#pragma unroll
        for (int ks = 0; ks < 2; ks++) {
            bf16x8 pa = *(const bf16x8*)&Ps[(w * 16 + l15) * P2 + ks * 32 + quad * 8];
#pragma unroll
            for (int ct = 0; ct < 4; ct++) {
                bf16x8 vb = *(const bf16x8*)&Vt[(ct * 16 + l15) * P2 + ks * 32 + quad * 8];
                oacc[ct] = __builtin_amdgcn_mfma_f32_16x16x32_bf16(pa, vb, oacc[ct], 0, 0, 0);
            }
        }
    }

    // ---- epilogue: normalize, merged-head store ----
    float inv[4];
#pragma unroll
    for (int r = 0; r < 4; r++) inv[r] = 1.0f / lrow[r];
#pragma unroll
    for (int ct = 0; ct < 4; ct++)
#pragma unroll
        for (int r = 0; r < 4; r++)
            ao[(size_t)b * SS * DD + (size_t)(q0 + w * 16 + quad * 4 + r) * DD +
               h * DP + ct * 16 + l15] = oacc[ct][r] * inv[r];
}

// ---------------------------------------------------------------------------
extern "C" void kernel_launch(void* const* d_in, const int* in_sizes, int n_in,
                              void* d_out, int out_size, void* d_ws, size_t ws_size,
                              hipStream_t stream)
{
    const float* q    = (const float*)d_in[0];
    const float* k    = (const float*)d_in[1];
    const float* v    = (const float*)d_in[2];
    const int*   mask = (const int*)d_in[3];
    const float* Wq_w = (const float*)d_in[4];
    const float* Wq_b = (const float*)d_in[5];
    const float* Wk_w = (const float*)d_in[6];
    const float* Wk_b = (const float*)d_in[7];
    const float* Wv_w = (const float*)d_in[8];
    const float* Wv_b = (const float*)d_in[9];
    const float* E    = (const float*)d_in[10];
    const float* Wo_w = (const float*)d_in[11];
    const float* Wo_b = (const float*)d_in[12];
    float* out = (float*)d_out;

    // workspace layout: qp | kp | vp | ao (fp32) | G (bf16)
    float* qp = (float*)d_ws;
    float* kp = qp + BSD;
    float* vp = kp + BSD;
    float* ao = vp + BSD;
    __hip_bfloat16* G = (__hip_bfloat16*)(ao + BSD);

    dim3 blk(256);
    dim3 pg(4096 / 64, 512 / 64);
    hipLaunchKernelGGL(gemm_xwT_512, pg, blk, 0, stream, q, Wq_w, Wq_b, qp);
    hipLaunchKernelGGL(gemm_xwT_512, pg, blk, 0, stream, k, Wk_w, Wk_b, kp);
    hipLaunchKernelGGL(gemm_xwT_512, pg, blk, 0, stream, v, Wv_w, Wv_b, vp);
    hipLaunchKernelGGL(relg_kernel, dim3(SS / 64, MR / 64, 16), blk, 0, stream, qp, E, G);
    hipLaunchKernelGGL(attn_kernel, dim3(16, SS / 64), blk, 0, stream, qp, kp, vp, mask, G, ao);
    hipLaunchKernelGGL(gemm_xwT_512, pg, blk, 0, stream, ao, Wo_w, Wo_b, out);
}

// Round 3
// 405.131 us; speedup vs baseline: 5.8076x; 1.2837x over previous
//
#include <hip/hip_runtime.h>
#include <hip/hip_bf16.h>

#define BB 2
#define SS 2048
#define DD 512
#define HH 8
#define DP 64
#define MR 1024

typedef __attribute__((ext_vector_type(8))) short bf16x8;
typedef __attribute__((ext_vector_type(4))) float floatx4;

static __device__ __forceinline__ unsigned short f2b(float x) {
    __hip_bfloat16 h = __float2bfloat16(x);
    return *reinterpret_cast<unsigned short*>(&h);
}
static __device__ __forceinline__ float b2f(unsigned short u) {
    __hip_bfloat16 h = *reinterpret_cast<__hip_bfloat16*>(&u);
    return __bfloat162float(h);
}
// async global->LDS, 16B per lane; LDS dest = wave-uniform base + lane*16
static __device__ __forceinline__ void gll16(const void* g, void* l) {
    __builtin_amdgcn_global_load_lds(
        (const __attribute__((address_space(1))) void*)g,
        (__attribute__((address_space(3))) void*)l, 16, 0, 0);
}

// ---------------------------------------------------------------------------
// bf16-MFMA GEMM: C[m][n] = sum_k X[m][k]*W[n][k] + bias[n]. M=4096,N=512,K=512.
// Grid (64,8), block 256 (4 waves, each 32x32). K-step 32, LDS pitch 40 (80B).
// ---------------------------------------------------------------------------
template <bool XBF16, bool OBF16>
__global__ __launch_bounds__(256) void gemm_xwT(
    const void* __restrict__ Xv, const float* __restrict__ W,
    const float* __restrict__ bias, void* __restrict__ Cv)
{
    __shared__ unsigned short Xs[64 * 40];
    __shared__ unsigned short Ws[64 * 40];
    const int t = threadIdx.x;
    const int lane = t & 63, w = t >> 6;
    const int quad = lane >> 4, l15 = lane & 15;
    const int wm = w >> 1, wn = w & 1;
    const int m0 = blockIdx.x * 64, n0 = blockIdx.y * 64;
    const int srow = t >> 2, sc8 = (t & 3) * 8;

    floatx4 acc[2][2];
#pragma unroll
    for (int i = 0; i < 2; i++)
#pragma unroll
        for (int j = 0; j < 2; j++) acc[i][j] = (floatx4){0.f, 0.f, 0.f, 0.f};

    for (int k0 = 0; k0 < 512; k0 += 32) {
        if (k0) __syncthreads();
        if constexpr (XBF16) {
            const unsigned short* X = (const unsigned short*)Xv;
            *(uint4*)&Xs[srow * 40 + sc8] =
                *(const uint4*)&X[(size_t)(m0 + srow) * 512 + k0 + sc8];
        } else {
            const float* X = (const float*)Xv;
            float4 a = *(const float4*)&X[(size_t)(m0 + srow) * 512 + k0 + sc8];
            float4 c = *(const float4*)&X[(size_t)(m0 + srow) * 512 + k0 + sc8 + 4];
            alignas(16) unsigned short u[8] = {f2b(a.x), f2b(a.y), f2b(a.z), f2b(a.w),
                                               f2b(c.x), f2b(c.y), f2b(c.z), f2b(c.w)};
            *(uint4*)&Xs[srow * 40 + sc8] = *(const uint4*)u;
        }
        {
            float4 a = *(const float4*)&W[(size_t)(n0 + srow) * 512 + k0 + sc8];
            float4 c = *(const float4*)&W[(size_t)(n0 + srow) * 512 + k0 + sc8 + 4];
            alignas(16) unsigned short u[8] = {f2b(a.x), f2b(a.y), f2b(a.z), f2b(a.w),
                                               f2b(c.x), f2b(c.y), f2b(c.z), f2b(c.w)};
            *(uint4*)&Ws[srow * 40 + sc8] = *(const uint4*)u;
        }
        __syncthreads();
        bf16x8 a0 = *(const bf16x8*)&Xs[(wm * 32 + l15) * 40 + quad * 8];
        bf16x8 a1 = *(const bf16x8*)&Xs[(wm * 32 + 16 + l15) * 40 + quad * 8];
        bf16x8 b0 = *(const bf16x8*)&Ws[(wn * 32 + l15) * 40 + quad * 8];
        bf16x8 b1 = *(const bf16x8*)&Ws[(wn * 32 + 16 + l15) * 40 + quad * 8];
        acc[0][0] = __builtin_amdgcn_mfma_f32_16x16x32_bf16(a0, b0, acc[0][0], 0, 0, 0);
        acc[0][1] = __builtin_amdgcn_mfma_f32_16x16x32_bf16(a0, b1, acc[0][1], 0, 0, 0);
        acc[1][0] = __builtin_amdgcn_mfma_f32_16x16x32_bf16(a1, b0, acc[1][0], 0, 0, 0);
        acc[1][1] = __builtin_amdgcn_mfma_f32_16x16x32_bf16(a1, b1, acc[1][1], 0, 0, 0);
    }
#pragma unroll
    for (int sub = 0; sub < 2; sub++)
#pragma unroll
        for (int ct = 0; ct < 2; ct++) {
            const int n = n0 + wn * 32 + ct * 16 + l15;
            const float bv = bias[n];
#pragma unroll
            for (int r = 0; r < 4; r++) {
                const size_t m = (size_t)(m0 + wm * 32 + sub * 16 + quad * 4 + r);
                float val = acc[sub][ct][r] + bv;
                if constexpr (OBF16) ((unsigned short*)Cv)[m * 512 + n] = f2b(val);
                else                 ((float*)Cv)[m * 512 + n] = val;
            }
        }
}

// ---------------------------------------------------------------------------
// Relative logits: G[bh][i][t] = sum_d qp[b][i][h*64+d]*E[t][h*64+d] (bf16 out)
// Grid (32 i-tiles, 16 t-tiles, 16 bh), block 256. Single-shot K=64.
// ---------------------------------------------------------------------------
__global__ __launch_bounds__(256) void relg_kernel(
    const unsigned short* __restrict__ qp, const float* __restrict__ E,
    unsigned short* __restrict__ G)
{
    __shared__ unsigned short As[64 * 72];
    __shared__ unsigned short Bs[64 * 72];
    const int t = threadIdx.x;
    const int lane = t & 63, w = t >> 6;
    const int quad = lane >> 4, l15 = lane & 15;
    const int wm = w >> 1, wn = w & 1;
    const int bh = blockIdx.z, b = bh >> 3, h = bh & 7;
    const int i0 = blockIdx.x * 64, t0 = blockIdx.y * 64;
    const int srow = t >> 2, sc16 = (t & 3) * 16;

    const unsigned short* Ar = &qp[((size_t)(b * SS) + i0 + srow) * DD + h * DP + sc16];
    *(uint4*)&As[srow * 72 + sc16]     = *(const uint4*)&Ar[0];
    *(uint4*)&As[srow * 72 + sc16 + 8] = *(const uint4*)&Ar[8];
    {
        const float* Er = &E[(size_t)(t0 + srow) * DD + h * DP + sc16];
        float4 e0 = *(const float4*)&Er[0], e1 = *(const float4*)&Er[4];
        float4 e2 = *(const float4*)&Er[8], e3 = *(const float4*)&Er[12];
        alignas(16) unsigned short u[16] = {
            f2b(e0.x), f2b(e0.y), f2b(e0.z), f2b(e0.w),
            f2b(e1.x), f2b(e1.y), f2b(e1.z), f2b(e1.w),
            f2b(e2.x), f2b(e2.y), f2b(e2.z), f2b(e2.w),
            f2b(e3.x), f2b(e3.y), f2b(e3.z), f2b(e3.w)};
        *(uint4*)&Bs[srow * 72 + sc16]     = *(const uint4*)&u[0];
        *(uint4*)&Bs[srow * 72 + sc16 + 8] = *(const uint4*)&u[8];
    }
    __syncthreads();

    floatx4 acc[2][2];
#pragma unroll
    for (int i = 0; i < 2; i++)
#pragma unroll
        for (int j = 0; j < 2; j++) acc[i][j] = (floatx4){0.f, 0.f, 0.f, 0.f};
#pragma unroll
    for (int ks = 0; ks < 2; ks++) {
        bf16x8 a0 = *(const bf16x8*)&As[(wm * 32 + l15) * 72 + ks * 32 + quad * 8];
        bf16x8 a1 = *(const bf16x8*)&As[(wm * 32 + 16 + l15) * 72 + ks * 32 + quad * 8];
        bf16x8 b0 = *(const bf16x8*)&Bs[(wn * 32 + l15) * 72 + ks * 32 + quad * 8];
        bf16x8 b1 = *(const bf16x8*)&Bs[(wn * 32 + 16 + l15) * 72 + ks * 32 + quad * 8];
        acc[0][0] = __builtin_amdgcn_mfma_f32_16x16x32_bf16(a0, b0, acc[0][0], 0, 0, 0);
        acc[0][1] = __builtin_amdgcn_mfma_f32_16x16x32_bf16(a0, b1, acc[0][1], 0, 0, 0);
        acc[1][0] = __builtin_amdgcn_mfma_f32_16x16x32_bf16(a1, b0, acc[1][0], 0, 0, 0);
        acc[1][1] = __builtin_amdgcn_mfma_f32_16x16x32_bf16(a1, b1, acc[1][1], 0, 0, 0);
    }
#pragma unroll
    for (int sub = 0; sub < 2; sub++)
#pragma unroll
        for (int ct = 0; ct < 2; ct++)
#pragma unroll
            for (int r = 0; r < 4; r++)
                G[((size_t)bh * SS + i0 + wm * 32 + sub * 16 + quad * 4 + r) * MR +
                  t0 + wn * 32 + ct * 16 + l15] = f2b(acc[sub][ct][r]);
}

// ---------------------------------------------------------------------------
// V transpose: vp[b][s][h*64+d] (bf16) -> vpT[bh][d][s] (bf16). Grid (32,16).
// ---------------------------------------------------------------------------
__global__ __launch_bounds__(256) void vtrans_kernel(
    const unsigned short* __restrict__ vp, unsigned short* __restrict__ vpT)
{
    __shared__ unsigned short T[64 * 72];
    const int t = threadIdx.x;
    const int bh = blockIdx.y, b = bh >> 3, h = bh & 7;
    const int s0 = blockIdx.x * 64;
    const int srow = t >> 2, sc16 = (t & 3) * 16;

    const unsigned short* Vr = &vp[((size_t)(b * SS) + s0 + srow) * DD + h * DP + sc16];
    *(uint4*)&T[srow * 72 + sc16]     = *(const uint4*)&Vr[0];
    *(uint4*)&T[srow * 72 + sc16 + 8] = *(const uint4*)&Vr[8];
    __syncthreads();

    alignas(16) unsigned short u[16];
#pragma unroll
    for (int j = 0; j < 16; j++) u[j] = T[(sc16 + j) * 72 + srow];
    unsigned short* Orow = &vpT[((size_t)bh * DP + srow) * SS + s0 + sc16];
    *(uint4*)&Orow[0] = *(const uint4*)&u[0];
    *(uint4*)&Orow[8] = *(const uint4*)&u[8];
}

// ---------------------------------------------------------------------------
// Mask bitpack: one wave per 64-bit word via ballot. Grid (32768), block 256.
// ---------------------------------------------------------------------------
__global__ __launch_bounds__(256) void maskpack_kernel(
    const int* __restrict__ mask, unsigned long long* __restrict__ bits)
{
    const size_t wid = (size_t)blockIdx.x * 4 + (threadIdx.x >> 6);
    const int lane = threadIdx.x & 63;
    const int mv = mask[wid * 64 + lane];
    unsigned long long bal = __ballot(mv != 0);
    if (lane == 0) bits[wid] = bal;
}

// ---------------------------------------------------------------------------
// Flash attention, bf16 MFMA, async swizzled staging, bitmask, G-table skew.
// Grid (16 bh, 32 qtiles), block 256 (4 waves x 16 Q rows).
// LDS: Ks 8K + Vt 8K + PQ 9.2K + d0s + Mw ~ 26.3 KB.
// ---------------------------------------------------------------------------
__global__ __launch_bounds__(256) void attn_kernel(
    const unsigned short* __restrict__ qp, const unsigned short* __restrict__ kp,
    const unsigned short* __restrict__ vpT, const unsigned long long* __restrict__ mbits,
    const unsigned short* __restrict__ G, unsigned short* __restrict__ ao)
{
    __shared__ unsigned short Ks[64 * 64];
    __shared__ unsigned short Vt[64 * 64];
    __shared__ unsigned short PQ[64 * 72];   // Q (swizzled, pitch 128B), then P strips (pitch 144B)
    __shared__ float d0s[66];
    __shared__ unsigned long long Mw[64];

    const int t = threadIdx.x, w = t >> 6, lane = t & 63;
    const int quad = lane >> 4, l15 = lane & 15;
    const int bh = blockIdx.x, b = bh >> 3, h = bh & 7;
    const int q0 = blockIdx.y * 64;

    const unsigned short* qb = qp + (size_t)b * SS * DD + h * DP;
    const unsigned short* kb = kp + (size_t)b * SS * DD + h * DP;
    const unsigned short* vb = vpT + (size_t)bh * DP * SS;
    const unsigned short* Gb = G + (size_t)bh * SS * MR;
    const unsigned long long* mb = mbits + (size_t)b * SS * (SS / 64);

    // staging chunk geometry: chunk p -> row p>>3, logical 8-elem col (p&7)^(row&7)
    const int p0 = w * 128 + lane, p1 = p0 + 64;
    const int r0 = p0 >> 3, c0 = (p0 & 7) ^ (r0 & 7);
    const int r1 = p1 >> 3, c1 = (p1 & 7) ^ (r1 & 7);
    const size_t koff0 = (size_t)r0 * DD + c0 * 8;
    const size_t koff1 = (size_t)r1 * DD + c1 * 8;
    const size_t voff0 = (size_t)r0 * SS + c0 * 8;
    const size_t voff1 = (size_t)r1 * SS + c1 * 8;
    char* KsB = (char*)Ks;
    char* VtB = (char*)Vt;
    char* PQB = (char*)PQ;

    // ---- stage Q (async, swizzled) + d0 column ----
    gll16(qb + (size_t)(q0 + r0) * DD + c0 * 8, PQB + w * 2048);
    gll16(qb + (size_t)(q0 + r1) * DD + c1 * 8, PQB + w * 2048 + 1024);
    if (t < 66) {
        int gi = q0 + t; if (gi > SS - 1) gi = SS - 1;
        d0s[t] = b2f(Gb[(size_t)gi * MR]);
    }
    __syncthreads();

    const int xr = l15 & 7;
    const int x0 = 16 * (quad ^ xr);
    const int x1 = 16 * ((4 + quad) ^ xr);

    bf16x8 qf0 = *(const bf16x8*)(PQB + (w * 16 + l15) * 128 + x0);
    bf16x8 qf1 = *(const bf16x8*)(PQB + (w * 16 + l15) * 128 + x1);

    float d0a[4], d0b[4];
    int gia[4];
#pragma unroll
    for (int r = 0; r < 4; r++) {
        const int i = w * 16 + quad * 4 + r;
        d0a[r] = d0s[i];
        d0b[r] = d0s[i + 1];
        gia[r] = q0 + i;
    }

    floatx4 oacc[4];
#pragma unroll
    for (int ct = 0; ct < 4; ct++) oacc[ct] = (floatx4){0.f, 0.f, 0.f, 0.f};
    float mrow[4] = {-3.0e38f, -3.0e38f, -3.0e38f, -3.0e38f};
    float lrow[4] = {0.f, 0.f, 0.f, 0.f};

    for (int ti = 0; ti < 32; ti++) {
        const int k0 = ti * 64;
        __syncthreads();   // prior iteration's LDS reads done
        if (t < 64) Mw[t] = mb[(size_t)(q0 + t) * (SS / 64) + ti];
        gll16(kb + (size_t)k0 * DD + koff0, KsB + w * 2048);
        gll16(kb + (size_t)k0 * DD + koff1, KsB + w * 2048 + 1024);
        gll16(vb + (size_t)k0 + voff0, VtB + w * 2048);
        gll16(vb + (size_t)k0 + voff1, VtB + w * 2048 + 1024);
        __syncthreads();

        unsigned long long mwv[4];
#pragma unroll
        for (int r = 0; r < 4; r++) mwv[r] = Mw[w * 16 + quad * 4 + r];

        const bool farpast = (q0 - (k0 + 63)) >= MR;

        // C-init: unscaled rel + mask * (NEG_INF/kScale)
        floatx4 acc[4];
#pragma unroll
        for (int ct = 0; ct < 4; ct++) {
#pragma unroll
            for (int r = 0; r < 4; r++) {
                float rel;
                if (farpast) {
                    rel = d0a[r];
                } else {
                    const int gj = k0 + ct * 16 + l15;
                    const int dd = gia[r] - gj;
                    int grow, gidx;
                    if (dd < 0) {
                        grow = gia[r] + 1; if (grow > SS - 1) grow = SS - 1;
                        gidx = -dd - (MR + 2); if (gidx < 0) gidx = 0;
                    } else {
                        grow = gia[r];
                        gidx = MR - 1 - dd; if (gidx < 0) gidx = 0;
                    }
                    rel = b2f(Gb[(size_t)grow * MR + gidx]);
                    if (dd == -1) rel = 0.0f;
                }
                const unsigned int half =
                    (unsigned int)((ct < 2) ? (mwv[r] & 0xffffffffULL) : (mwv[r] >> 32));
                const float mneg = ((half >> ((ct & 1) * 16 + l15)) & 1u) ? -8.0e9f : 0.0f;
                acc[ct][r] = rel + mneg;
            }
        }

        // ---- QK^T ----
#pragma unroll
        for (int ct = 0; ct < 4; ct++) {
            bf16x8 bf = *(const bf16x8*)(KsB + (ct * 16 + l15) * 128 + x0);
            acc[ct] = __builtin_amdgcn_mfma_f32_16x16x32_bf16(qf0, bf, acc[ct], 0, 0, 0);
        }
#pragma unroll
        for (int ct = 0; ct < 4; ct++) {
            bf16x8 bf = *(const bf16x8*)(KsB + (ct * 16 + l15) * 128 + x1);
            acc[ct] = __builtin_amdgcn_mfma_f32_16x16x32_bf16(qf1, bf, acc[ct], 0, 0, 0);
        }

        // ---- online softmax on unscaled logits (scale folded into exp) ----
        float alpha[4], pm[4][4];
#pragma unroll
        for (int r = 0; r < 4; r++) {
            const float s0 = acc[0][r], s1 = acc[1][r], s2 = acc[2][r], s3 = acc[3][r];
            float mx = fmaxf(fmaxf(s0, s1), fmaxf(s2, s3));
            mx = fmaxf(mx, __shfl_xor(mx, 1));
            mx = fmaxf(mx, __shfl_xor(mx, 2));
            mx = fmaxf(mx, __shfl_xor(mx, 4));
            mx = fmaxf(mx, __shfl_xor(mx, 8));
            const float mnew = fmaxf(mrow[r], mx);
            alpha[r] = __expf((mrow[r] - mnew) * 0.125f);
            mrow[r] = mnew;
            const float p0 = __expf((s0 - mnew) * 0.125f);
            const float p1 = __expf((s1 - mnew) * 0.125f);
            const float p2 = __expf((s2 - mnew) * 0.125f);
            const float p3 = __expf((s3 - mnew) * 0.125f);
            pm[0][r] = p0; pm[1][r] = p1; pm[2][r] = p2; pm[3][r] = p3;
            float ps = p0 + p1 + p2 + p3;
            ps += __shfl_xor(ps, 1);
            ps += __shfl_xor(ps, 2);
            ps += __shfl_xor(ps, 4);
            ps += __shfl_xor(ps, 8);
            lrow[r] = lrow[r] * alpha[r] + ps;
        }

        // ---- P strip (wave-private rows, pitch 72) ----
#pragma unroll
        for (int ct = 0; ct < 4; ct++)
#pragma unroll
            for (int r = 0; r < 4; r++)
                PQ[(w * 16 + quad * 4 + r) * 72 + ct * 16 + l15] = f2b(pm[ct][r]);

#pragma unroll
        for (int ct = 0; ct < 4; ct++)
#pragma unroll
            for (int r = 0; r < 4; r++) oacc[ct][r] *= alpha[r];

        // ---- PV ----
        bf16x8 pa0 = *(const bf16x8*)(PQB + ((w * 16 + l15) * 72 + quad * 8) * 2);
        bf16x8 pa1 = *(const bf16x8*)(PQB + ((w * 16 + l15) * 72 + 32 + quad * 8) * 2);
#pragma unroll
        for (int ct = 0; ct < 4; ct++) {
            bf16x8 vb0 = *(const bf16x8*)(VtB + (ct * 16 + l15) * 128 + x0);
            oacc[ct] = __builtin_amdgcn_mfma_f32_16x16x32_bf16(pa0, vb0, oacc[ct], 0, 0, 0);
        }
#pragma unroll
        for (int ct = 0; ct < 4; ct++) {
            bf16x8 vb1 = *(const bf16x8*)(VtB + (ct * 16 + l15) * 128 + x1);
            oacc[ct] = __builtin_amdgcn_mfma_f32_16x16x32_bf16(pa1, vb1, oacc[ct], 0, 0, 0);
        }
    }

    float inv[4];
#pragma unroll
    for (int r = 0; r < 4; r++) inv[r] = 1.0f / lrow[r];
#pragma unroll
    for (int ct = 0; ct < 4; ct++)
#pragma unroll
        for (int r = 0; r < 4; r++)
            ao[((size_t)b * SS + q0 + w * 16 + quad * 4 + r) * DD + h * DP + ct * 16 + l15] =
                f2b(oacc[ct][r] * inv[r]);
}

// ---------------------------------------------------------------------------
extern "C" void kernel_launch(void* const* d_in, const int* in_sizes, int n_in,
                              void* d_out, int out_size, void* d_ws, size_t ws_size,
                              hipStream_t stream)
{
    const float* q    = (const float*)d_in[0];
    const float* k    = (const float*)d_in[1];
    const float* v    = (const float*)d_in[2];
    const int*   mask = (const int*)d_in[3];
    const float* Wq_w = (const float*)d_in[4];
    const float* Wq_b = (const float*)d_in[5];
    const float* Wk_w = (const float*)d_in[6];
    const float* Wk_b = (const float*)d_in[7];
    const float* Wv_w = (const float*)d_in[8];
    const float* Wv_b = (const float*)d_in[9];
    const float* E    = (const float*)d_in[10];
    const float* Wo_w = (const float*)d_in[11];
    const float* Wo_b = (const float*)d_in[12];
    float* out = (float*)d_out;

    // ws layout (bytes): G 67108864 | qp/kp/vp/vpT/ao 5x4194304 | mbits 1048576
    char* ws = (char*)d_ws;
    unsigned short* G   = (unsigned short*)ws;
    unsigned short* qp  = (unsigned short*)(ws + 67108864);
    unsigned short* kp  = qp + 2097152;
    unsigned short* vp  = kp + 2097152;
    unsigned short* vpT = vp + 2097152;
    unsigned short* aob = vpT + 2097152;
    unsigned long long* mbits = (unsigned long long*)(ws + 67108864 + 5 * 4194304);

    dim3 blk(256);
    dim3 pg(64, 8);
    hipLaunchKernelGGL((gemm_xwT<false, true>), pg, blk, 0, stream, (const void*)q, Wq_w, Wq_b, (void*)qp);
    hipLaunchKernelGGL((gemm_xwT<false, true>), pg, blk, 0, stream, (const void*)k, Wk_w, Wk_b, (void*)kp);
    hipLaunchKernelGGL((gemm_xwT<false, true>), pg, blk, 0, stream, (const void*)v, Wv_w, Wv_b, (void*)vp);
    hipLaunchKernelGGL(vtrans_kernel, dim3(32, 16), blk, 0, stream, vp, vpT);
    hipLaunchKernelGGL(relg_kernel, dim3(32, 16, 16), blk, 0, stream, qp, E, G);
    hipLaunchKernelGGL(maskpack_kernel, dim3(32768), blk, 0, stream, mask, mbits);
    hipLaunchKernelGGL(attn_kernel, dim3(16, 32), blk, 0, stream, qp, kp, vpT, mbits, G, aob);
    hipLaunchKernelGGL((gemm_xwT<true, false>), pg, blk, 0, stream, (const void*)aob, Wo_w, Wo_b, (void*)out);
}

// Round 4
// 335.653 us; speedup vs baseline: 7.0097x; 1.2070x over previous
//
#include <hip/hip_runtime.h>
#include <hip/hip_bf16.h>

#define BB 2
#define SS 2048
#define DD 512
#define HH 8
#define DP 64
#define MR 1024

typedef __attribute__((ext_vector_type(8))) short bf16x8;
typedef __attribute__((ext_vector_type(4))) float floatx4;

static __device__ __forceinline__ unsigned short f2b(float x) {
    __hip_bfloat16 h = __float2bfloat16(x);
    return *reinterpret_cast<unsigned short*>(&h);
}
static __device__ __forceinline__ float b2f(unsigned short u) {
    __hip_bfloat16 h = *reinterpret_cast<__hip_bfloat16*>(&u);
    return __bfloat162float(h);
}
// async global->LDS, 16B per lane; LDS dest = wave-uniform base + lane*16
static __device__ __forceinline__ void gll16(const void* g, void* l) {
    __builtin_amdgcn_global_load_lds(
        (const __attribute__((address_space(1))) void*)g,
        (__attribute__((address_space(3))) void*)l, 16, 0, 0);
}
// XOR-swizzled byte offset inside a 64-row x 64-col bf16 tile (128 B pitch)
static __device__ __forceinline__ int xoff(int ks, int quad, int row) {
    return (((ks * 4 + quad) ^ (row & 7)) * 16);
}

// ---------------------------------------------------------------------------
// prep: convert Wq,Wk,Wv,Wo (512x512) and E (1024x512) fp32 -> bf16.
// Grid 1536 x 256, 4 elems/thread.
// ---------------------------------------------------------------------------
__global__ __launch_bounds__(256) void prep_kernel(
    const float* __restrict__ Wq, const float* __restrict__ Wk,
    const float* __restrict__ Wv, const float* __restrict__ Wo,
    const float* __restrict__ E,
    unsigned short* __restrict__ Wqb, unsigned short* __restrict__ Wkb,
    unsigned short* __restrict__ Wvb, unsigned short* __restrict__ Wob,
    unsigned short* __restrict__ Eb)
{
    const int gid = blockIdx.x * 256 + threadIdx.x;   // 0..393215
    const int N1 = 65536;                              // 262144/4
    const float* src; unsigned short* dst; int off;
    if      (gid < 1 * N1) { src = Wq; dst = Wqb; off = gid; }
    else if (gid < 2 * N1) { src = Wk; dst = Wkb; off = gid - 1 * N1; }
    else if (gid < 3 * N1) { src = Wv; dst = Wvb; off = gid - 2 * N1; }
    else if (gid < 4 * N1) { src = Wo; dst = Wob; off = gid - 3 * N1; }
    else                   { src = E;  dst = Eb;  off = gid - 4 * N1; }
    float4 v = ((const float4*)src)[off];
    ushort4 u; u.x = f2b(v.x); u.y = f2b(v.y); u.z = f2b(v.z); u.w = f2b(v.w);
    ((ushort4*)dst)[off] = u;
}

// ---------------------------------------------------------------------------
// Fused QKV projection: out = X @ W^T + b (bf16 out). Grid (64, 8, 3).
// X fp32 staged+converted; W bf16 staged async (swizzled). K-step 64.
// ---------------------------------------------------------------------------
__global__ __launch_bounds__(256) void gemm_proj(
    const float* __restrict__ Xq, const float* __restrict__ Xk,
    const float* __restrict__ Xv,
    const unsigned short* __restrict__ Wqb, const unsigned short* __restrict__ Wkb,
    const unsigned short* __restrict__ Wvb,
    const float* __restrict__ bq, const float* __restrict__ bk,
    const float* __restrict__ bv,
    unsigned short* __restrict__ qp, unsigned short* __restrict__ kp,
    unsigned short* __restrict__ vp)
{
    const int z = blockIdx.z;
    const float* X = (z == 0) ? Xq : (z == 1) ? Xk : Xv;
    const unsigned short* Wb = (z == 0) ? Wqb : (z == 1) ? Wkb : Wvb;
    const float* bias = (z == 0) ? bq : (z == 1) ? bk : bv;
    unsigned short* Out = (z == 0) ? qp : (z == 1) ? kp : vp;

    __shared__ unsigned short Xs[64 * 72];
    __shared__ unsigned short Ws[64 * 64];
    char* WsB = (char*)Ws;
    const int t = threadIdx.x, lane = t & 63, w = t >> 6;
    const int quad = lane >> 4, l15 = lane & 15;
    const int wm = w >> 1, wn = w & 1;
    const int m0 = blockIdx.x * 64, n0 = blockIdx.y * 64;
    const int srow = t >> 2, sseg = t & 3;

    // W staging chunk geometry (2 gll16 per wave per step)
    int wrow[2], wcol[2];
#pragma unroll
    for (int i = 0; i < 2; i++) {
        const int c = w * 128 + i * 64 + lane;
        wrow[i] = c >> 3; wcol[i] = (c & 7) ^ (wrow[i] & 7);
    }

    floatx4 acc[2][2];
#pragma unroll
    for (int i = 0; i < 2; i++)
#pragma unroll
        for (int j = 0; j < 2; j++) acc[i][j] = (floatx4){0.f, 0.f, 0.f, 0.f};

    for (int k0 = 0; k0 < 512; k0 += 64) {
        if (k0) __syncthreads();
        {
            const float* Xr = X + (size_t)(m0 + srow) * 512 + k0 + sseg * 16;
            float4 a = *(const float4*)&Xr[0];
            float4 b = *(const float4*)&Xr[4];
            float4 c = *(const float4*)&Xr[8];
            float4 d = *(const float4*)&Xr[12];
            alignas(16) unsigned short u[16] = {
                f2b(a.x), f2b(a.y), f2b(a.z), f2b(a.w),
                f2b(b.x), f2b(b.y), f2b(b.z), f2b(b.w),
                f2b(c.x), f2b(c.y), f2b(c.z), f2b(c.w),
                f2b(d.x), f2b(d.y), f2b(d.z), f2b(d.w)};
            *(uint4*)&Xs[srow * 72 + sseg * 16]     = *(const uint4*)&u[0];
            *(uint4*)&Xs[srow * 72 + sseg * 16 + 8] = *(const uint4*)&u[8];
        }
#pragma unroll
        for (int i = 0; i < 2; i++)
            gll16(Wb + (size_t)(n0 + wrow[i]) * 512 + k0 + wcol[i] * 8,
                  WsB + (w * 2 + i) * 1024);
        __syncthreads();
#pragma unroll
        for (int ks = 0; ks < 2; ks++) {
            bf16x8 a0 = *(const bf16x8*)&Xs[(wm * 32 + l15) * 72 + ks * 32 + quad * 8];
            bf16x8 a1 = *(const bf16x8*)&Xs[(wm * 32 + 16 + l15) * 72 + ks * 32 + quad * 8];
            bf16x8 b0 = *(const bf16x8*)(WsB + (wn * 32 + l15) * 128 + xoff(ks, quad, l15));
            bf16x8 b1 = *(const bf16x8*)(WsB + (wn * 32 + 16 + l15) * 128 + xoff(ks, quad, l15));
            acc[0][0] = __builtin_amdgcn_mfma_f32_16x16x32_bf16(a0, b0, acc[0][0], 0, 0, 0);
            acc[0][1] = __builtin_amdgcn_mfma_f32_16x16x32_bf16(a0, b1, acc[0][1], 0, 0, 0);
            acc[1][0] = __builtin_amdgcn_mfma_f32_16x16x32_bf16(a1, b0, acc[1][0], 0, 0, 0);
            acc[1][1] = __builtin_amdgcn_mfma_f32_16x16x32_bf16(a1, b1, acc[1][1], 0, 0, 0);
        }
    }
#pragma unroll
    for (int sub = 0; sub < 2; sub++)
#pragma unroll
        for (int ct = 0; ct < 2; ct++) {
            const int n = n0 + wn * 32 + ct * 16 + l15;
            const float bvl = bias[n];
#pragma unroll
            for (int r = 0; r < 4; r++) {
                const size_t m = (size_t)(m0 + wm * 32 + sub * 16 + quad * 4 + r);
                Out[m * 512 + n] = f2b(acc[sub][ct][r] + bvl);
            }
        }
}

// ---------------------------------------------------------------------------
// Output projection: out = A @ Wo^T + b (fp32 out, A bf16). Grid (64, 8).
// Both operands staged async (swizzled). K-step 64.
// ---------------------------------------------------------------------------
__global__ __launch_bounds__(256) void gemm_out(
    const unsigned short* __restrict__ A, const unsigned short* __restrict__ Wb,
    const float* __restrict__ bias, float* __restrict__ Out)
{
    __shared__ unsigned short As[64 * 64];
    __shared__ unsigned short Ws[64 * 64];
    char* AsB = (char*)As;
    char* WsB = (char*)Ws;
    const int t = threadIdx.x, lane = t & 63, w = t >> 6;
    const int quad = lane >> 4, l15 = lane & 15;
    const int wm = w >> 1, wn = w & 1;
    const int m0 = blockIdx.x * 64, n0 = blockIdx.y * 64;

    int wrow[2], wcol[2];
#pragma unroll
    for (int i = 0; i < 2; i++) {
        const int c = w * 128 + i * 64 + lane;
        wrow[i] = c >> 3; wcol[i] = (c & 7) ^ (wrow[i] & 7);
    }

    floatx4 acc[2][2];
#pragma unroll
    for (int i = 0; i < 2; i++)
#pragma unroll
        for (int j = 0; j < 2; j++) acc[i][j] = (floatx4){0.f, 0.f, 0.f, 0.f};

    for (int k0 = 0; k0 < 512; k0 += 64) {
        if (k0) __syncthreads();
#pragma unroll
        for (int i = 0; i < 2; i++) {
            gll16(A  + (size_t)(m0 + wrow[i]) * 512 + k0 + wcol[i] * 8,
                  AsB + (w * 2 + i) * 1024);
            gll16(Wb + (size_t)(n0 + wrow[i]) * 512 + k0 + wcol[i] * 8,
                  WsB + (w * 2 + i) * 1024);
        }
        __syncthreads();
#pragma unroll
        for (int ks = 0; ks < 2; ks++) {
            bf16x8 a0 = *(const bf16x8*)(AsB + (wm * 32 + l15) * 128 + xoff(ks, quad, l15));
            bf16x8 a1 = *(const bf16x8*)(AsB + (wm * 32 + 16 + l15) * 128 + xoff(ks, quad, l15));
            bf16x8 b0 = *(const bf16x8*)(WsB + (wn * 32 + l15) * 128 + xoff(ks, quad, l15));
            bf16x8 b1 = *(const bf16x8*)(WsB + (wn * 32 + 16 + l15) * 128 + xoff(ks, quad, l15));
            acc[0][0] = __builtin_amdgcn_mfma_f32_16x16x32_bf16(a0, b0, acc[0][0], 0, 0, 0);
            acc[0][1] = __builtin_amdgcn_mfma_f32_16x16x32_bf16(a0, b1, acc[0][1], 0, 0, 0);
            acc[1][0] = __builtin_amdgcn_mfma_f32_16x16x32_bf16(a1, b0, acc[1][0], 0, 0, 0);
            acc[1][1] = __builtin_amdgcn_mfma_f32_16x16x32_bf16(a1, b1, acc[1][1], 0, 0, 0);
        }
    }
#pragma unroll
    for (int sub = 0; sub < 2; sub++)
#pragma unroll
        for (int ct = 0; ct < 2; ct++) {
            const int n = n0 + wn * 32 + ct * 16 + l15;
            const float bvl = bias[n];
#pragma unroll
            for (int r = 0; r < 4; r++) {
                const size_t m = (size_t)(m0 + wm * 32 + sub * 16 + quad * 4 + r);
                Out[m * 512 + n] = acc[sub][ct][r] + bvl;
            }
        }
}

// ---------------------------------------------------------------------------
// Relative logits, LDS-free: G[bh][i][t] = qp_row_i . Ebf_row_t (head slice).
// Grid (32, 16, 16), block 256 (4 waves x 16 i-rows). Write-bound (67 MB).
// ---------------------------------------------------------------------------
__global__ __launch_bounds__(256) void relg_kernel(
    const unsigned short* __restrict__ qp, const unsigned short* __restrict__ Eb,
    unsigned short* __restrict__ G)
{
    const int t = threadIdx.x, lane = t & 63, w = t >> 6;
    const int quad = lane >> 4, l15 = lane & 15;
    const int bh = blockIdx.z, b = bh >> 3, h = bh & 7;
    const int i0 = blockIdx.x * 64 + w * 16, t0 = blockIdx.y * 64;

    const unsigned short* Ar = qp + ((size_t)b * SS + i0 + l15) * DD + h * DP;
    bf16x8 a0 = *(const bf16x8*)(Ar + quad * 8);
    bf16x8 a1 = *(const bf16x8*)(Ar + 32 + quad * 8);

    floatx4 acc[4];
#pragma unroll
    for (int ct = 0; ct < 4; ct++) acc[ct] = (floatx4){0.f, 0.f, 0.f, 0.f};
#pragma unroll
    for (int ct = 0; ct < 4; ct++) {
        const unsigned short* Br = Eb + (size_t)(t0 + ct * 16 + l15) * DD + h * DP;
        bf16x8 b0 = *(const bf16x8*)(Br + quad * 8);
        bf16x8 b1 = *(const bf16x8*)(Br + 32 + quad * 8);
        acc[ct] = __builtin_amdgcn_mfma_f32_16x16x32_bf16(a0, b0, acc[ct], 0, 0, 0);
        acc[ct] = __builtin_amdgcn_mfma_f32_16x16x32_bf16(a1, b1, acc[ct], 0, 0, 0);
    }
#pragma unroll
    for (int ct = 0; ct < 4; ct++)
#pragma unroll
        for (int r = 0; r < 4; r++)
            G[((size_t)bh * SS + i0 + quad * 4 + r) * MR + t0 + ct * 16 + l15] =
                f2b(acc[ct][r]);
}

// ---------------------------------------------------------------------------
// V transpose: vp[b][s][h*64+d] (bf16) -> vpT[bh][d][s] (bf16). Grid (32,16).
// ---------------------------------------------------------------------------
__global__ __launch_bounds__(256) void vtrans_kernel(
    const unsigned short* __restrict__ vp, unsigned short* __restrict__ vpT)
{
    __shared__ unsigned short T[64 * 72];
    const int t = threadIdx.x;
    const int bh = blockIdx.y, b = bh >> 3, h = bh & 7;
    const int s0 = blockIdx.x * 64;
    const int srow = t >> 2, sc16 = (t & 3) * 16;

    const unsigned short* Vr = &vp[((size_t)(b * SS) + s0 + srow) * DD + h * DP + sc16];
    *(uint4*)&T[srow * 72 + sc16]     = *(const uint4*)&Vr[0];
    *(uint4*)&T[srow * 72 + sc16 + 8] = *(const uint4*)&Vr[8];
    __syncthreads();

    alignas(16) unsigned short u[16];
#pragma unroll
    for (int j = 0; j < 16; j++) u[j] = T[(sc16 + j) * 72 + srow];
    unsigned short* Orow = &vpT[((size_t)bh * DP + srow) * SS + s0 + sc16];
    *(uint4*)&Orow[0] = *(const uint4*)&u[0];
    *(uint4*)&Orow[8] = *(const uint4*)&u[8];
}

// ---------------------------------------------------------------------------
// Mask bitpack: one wave per 64-bit word via ballot. Grid (32768), block 256.
// ---------------------------------------------------------------------------
__global__ __launch_bounds__(256) void maskpack_kernel(
    const int* __restrict__ mask, unsigned long long* __restrict__ bits)
{
    const size_t wid = (size_t)blockIdx.x * 4 + (threadIdx.x >> 6);
    const int lane = threadIdx.x & 63;
    const int mv = mask[wid * 64 + lane];
    unsigned long long bal = __ballot(mv != 0);
    if (lane == 0) bits[wid] = bal;
}

// ---------------------------------------------------------------------------
// Flash attention, k-split-2 for occupancy. Block = 256 thr = 4 waves:
// wave w -> q-strip wr=w>>1 (16 rows), k-half kh=w&1 (1024 keys, 16 tiles).
// Grid (64 qtiles of 32 rows, 16 bh) = 1024 blocks = 4/CU, 16 waves/CU (50%).
// LDS: K 2x8K (P strips overlay after QK) + V 2x8K (merge area after loop)
//      + Mw 512B + d0s 128B ~= 33.1 KB.
// ---------------------------------------------------------------------------
__global__ __launch_bounds__(256, 4) void attn_kernel(
    const unsigned short* __restrict__ qp, const unsigned short* __restrict__ kp,
    const unsigned short* __restrict__ vpT, const unsigned long long* __restrict__ mbits,
    const unsigned short* __restrict__ G, unsigned short* __restrict__ ao)
{
    __shared__ unsigned short Ks[2 * 4096];
    __shared__ unsigned short Vt[2 * 4096];
    __shared__ unsigned long long Mw[64];
    __shared__ float d0s[32];

    const int t = threadIdx.x, lane = t & 63, w = t >> 6;
    const int quad = lane >> 4, l15 = lane & 15;
    const int wr = w >> 1, kh = w & 1;
    const int soff = wr * 16;
    const int bh = blockIdx.y, b = bh >> 3, h = bh & 7;
    const int q0 = blockIdx.x * 32;

    const unsigned short* qb = qp + (size_t)b * SS * DD + h * DP;
    const unsigned short* kb = kp + (size_t)b * SS * DD + h * DP;
    const unsigned short* vb = vpT + (size_t)bh * DP * SS;
    const unsigned short* Gb = G + (size_t)bh * SS * MR;
    const unsigned long long* mb = mbits + (size_t)b * SS * (SS / 64);

    // ---- Q fragments direct from global ----
    const unsigned short* qrow = qb + (size_t)(q0 + soff + l15) * DD;
    bf16x8 qf0 = *(const bf16x8*)(qrow + quad * 8);
    bf16x8 qf1 = *(const bf16x8*)(qrow + 32 + quad * 8);

    if (t < 32) d0s[t] = b2f(Gb[(size_t)(q0 + t) * MR]);
    __syncthreads();

    float d0a[4]; int gia[4];
#pragma unroll
    for (int r = 0; r < 4; r++) {
        d0a[r] = d0s[soff + quad * 4 + r];
        gia[r] = q0 + soff + quad * 4 + r;
    }

    unsigned short* Khalf = Ks + kh * 4096;
    char* KhB = (char*)Khalf;
    char* VhB = (char*)(Vt + kh * 4096);
    unsigned short* Pbase = Khalf + wr * 2048;   // 2304 B used of 4096
    char* PbB = (char*)Pbase;

    // staging chunk geometry (4 K + 4 V gll16 per wave per tile)
    int crow[4]; size_t koff[4], voff[4];
#pragma unroll
    for (int i = 0; i < 4; i++) {
        const int c = wr * 256 + i * 64 + lane;
        crow[i] = c >> 3;
        const int col8 = (c & 7) ^ (crow[i] & 7);
        koff[i] = (size_t)crow[i] * DD + col8 * 8;
        voff[i] = (size_t)crow[i] * SS + col8 * 8;
    }
    const int xr = l15 & 7;
    const int x0 = 16 * (quad ^ xr);
    const int x1 = 16 * ((4 + quad) ^ xr);

    floatx4 oacc[4];
#pragma unroll
    for (int ct = 0; ct < 4; ct++) oacc[ct] = (floatx4){0.f, 0.f, 0.f, 0.f};
    float mrow[4] = {-3.0e38f, -3.0e38f, -3.0e38f, -3.0e38f};
    float lrow[4] = {0.f, 0.f, 0.f, 0.f};

    for (int it = 0; it < 16; it++) {
        const int ti = kh * 16 + it;
        const int k0 = ti * 64;
        __syncthreads();   // (1) everyone done with prev iter's K(P)/V reads
        if (lane < 16) Mw[w * 16 + lane] = mb[(size_t)(q0 + soff + lane) * 32 + ti];
#pragma unroll
        for (int i = 0; i < 4; i++)
            gll16(kb + (size_t)k0 * DD + koff[i], KhB + (wr * 4 + i) * 1024);
#pragma unroll
        for (int i = 0; i < 4; i++)
            gll16(vb + k0 + voff[i], VhB + (wr * 4 + i) * 1024);
        __syncthreads();   // (2) staging visible

        unsigned long long mwv[4];
#pragma unroll
        for (int r = 0; r < 4; r++) mwv[r] = Mw[w * 16 + quad * 4 + r];

        const bool farpast = (q0 + soff) - (k0 + 63) >= MR;

        // ---- C-init: unscaled rel + mask * (NEG_INF/kScale) ----
        floatx4 acc[4];
#pragma unroll
        for (int ct = 0; ct < 4; ct++) {
#pragma unroll
            for (int r = 0; r < 4; r++) {
                float rel;
                if (farpast) {
                    rel = d0a[r];
                } else {
                    const int gj = k0 + ct * 16 + l15;
                    const int dd = gia[r] - gj;
                    int grow, gidx;
                    if (dd < 0) {
                        grow = gia[r] + 1; if (grow > SS - 1) grow = SS - 1;
                        gidx = -dd - (MR + 2); if (gidx < 0) gidx = 0;
                    } else {
                        grow = gia[r];
                        gidx = MR - 1 - dd; if (gidx < 0) gidx = 0;
                    }
                    rel = b2f(Gb[(size_t)grow * MR + gidx]);
                    if (dd == -1) rel = 0.0f;
                }
                const unsigned int half =
                    (unsigned int)((ct < 2) ? (mwv[r] & 0xffffffffULL) : (mwv[r] >> 32));
                const float mneg = ((half >> ((ct & 1) * 16 + l15)) & 1u) ? -8.0e9f : 0.0f;
                acc[ct][r] = rel + mneg;
            }
        }

        // ---- QK^T ----
#pragma unroll
        for (int ct = 0; ct < 4; ct++) {
            bf16x8 bf = *(const bf16x8*)(KhB + (ct * 16 + l15) * 128 + x0);
            acc[ct] = __builtin_amdgcn_mfma_f32_16x16x32_bf16(qf0, bf, acc[ct], 0, 0, 0);
        }
#pragma unroll
        for (int ct = 0; ct < 4; ct++) {
            bf16x8 bf = *(const bf16x8*)(KhB + (ct * 16 + l15) * 128 + x1);
            acc[ct] = __builtin_amdgcn_mfma_f32_16x16x32_bf16(qf1, bf, acc[ct], 0, 0, 0);
        }

        // ---- online softmax (unscaled; scale folded into exp) ----
        float alpha[4], pm[4][4];
#pragma unroll
        for (int r = 0; r < 4; r++) {
            const float s0 = acc[0][r], s1 = acc[1][r], s2 = acc[2][r], s3 = acc[3][r];
            float mx = fmaxf(fmaxf(s0, s1), fmaxf(s2, s3));
            mx = fmaxf(mx, __shfl_xor(mx, 1));
            mx = fmaxf(mx, __shfl_xor(mx, 2));
            mx = fmaxf(mx, __shfl_xor(mx, 4));
            mx = fmaxf(mx, __shfl_xor(mx, 8));
            const float mnew = fmaxf(mrow[r], mx);
            alpha[r] = __expf((mrow[r] - mnew) * 0.125f);
            mrow[r] = mnew;
            const float p0 = __expf((s0 - mnew) * 0.125f);
            const float p1 = __expf((s1 - mnew) * 0.125f);
            const float p2 = __expf((s2 - mnew) * 0.125f);
            const float p3 = __expf((s3 - mnew) * 0.125f);
            pm[0][r] = p0; pm[1][r] = p1; pm[2][r] = p2; pm[3][r] = p3;
            float ps = p0 + p1 + p2 + p3;
            ps += __shfl_xor(ps, 1);
            ps += __shfl_xor(ps, 2);
            ps += __shfl_xor(ps, 4);
            ps += __shfl_xor(ps, 8);
            lrow[r] = lrow[r] * alpha[r] + ps;
        }

        __syncthreads();   // (3) pair done reading K -> safe to overlay P

        // ---- P strip into K region (wave-private; pitch 72 u16) ----
#pragma unroll
        for (int ct = 0; ct < 4; ct++)
#pragma unroll
            for (int r = 0; r < 4; r++)
                Pbase[(quad * 4 + r) * 72 + ct * 16 + l15] = f2b(pm[ct][r]);

#pragma unroll
        for (int ct = 0; ct < 4; ct++)
#pragma unroll
            for (int r = 0; r < 4; r++) oacc[ct][r] *= alpha[r];

        // ---- PV ----
        bf16x8 pa0 = *(const bf16x8*)(PbB + l15 * 144 + quad * 16);
        bf16x8 pa1 = *(const bf16x8*)(PbB + l15 * 144 + 64 + quad * 16);
#pragma unroll
        for (int ct = 0; ct < 4; ct++) {
            bf16x8 vb0 = *(const bf16x8*)(VhB + (ct * 16 + l15) * 128 + x0);
            oacc[ct] = __builtin_amdgcn_mfma_f32_16x16x32_bf16(pa0, vb0, oacc[ct], 0, 0, 0);
        }
#pragma unroll
        for (int ct = 0; ct < 4; ct++) {
            bf16x8 vb1 = *(const bf16x8*)(VhB + (ct * 16 + l15) * 128 + x1);
            oacc[ct] = __builtin_amdgcn_mfma_f32_16x16x32_bf16(pa1, vb1, oacc[ct], 0, 0, 0);
        }
    }

    // ---- k-split merge (exchange via Vt region) ----
    __syncthreads();
    float* Xch = (float*)((char*)Vt + wr * 8192);
    if (kh == 1) {
#pragma unroll
        for (int ct = 0; ct < 4; ct++)
            *(floatx4*)&Xch[lane * 16 + ct * 4] = oacc[ct];
        if (l15 == 0) {
            float* ml = Xch + 1024;
#pragma unroll
            for (int r = 0; r < 4; r++) {
                ml[quad * 4 + r]      = mrow[r];
                ml[16 + quad * 4 + r] = lrow[r];
            }
        }
    }
    __syncthreads();
    if (kh == 0) {
        const float* ml = Xch + 1024;
        float a0[4], a1[4], inv[4];
#pragma unroll
        for (int r = 0; r < 4; r++) {
            const float m1 = ml[quad * 4 + r];
            const float l1 = ml[16 + quad * 4 + r];
            const float m = fmaxf(mrow[r], m1);
            a0[r] = __expf((mrow[r] - m) * 0.125f);
            a1[r] = __expf((m1 - m) * 0.125f);
            inv[r] = 1.0f / (lrow[r] * a0[r] + l1 * a1[r]);
        }
#pragma unroll
        for (int ct = 0; ct < 4; ct++) {
            floatx4 o1 = *(const floatx4*)&Xch[lane * 16 + ct * 4];
#pragma unroll
            for (int r = 0; r < 4; r++) {
                const float val = (oacc[ct][r] * a0[r] + o1[r] * a1[r]) * inv[r];
                ao[((size_t)b * SS + q0 + soff + quad * 4 + r) * DD +
                   h * DP + ct * 16 + l15] = f2b(val);
            }
        }
    }
}

// ---------------------------------------------------------------------------
extern "C" void kernel_launch(void* const* d_in, const int* in_sizes, int n_in,
                              void* d_out, int out_size, void* d_ws, size_t ws_size,
                              hipStream_t stream)
{
    const float* q    = (const float*)d_in[0];
    const float* k    = (const float*)d_in[1];
    const float* v    = (const float*)d_in[2];
    const int*   mask = (const int*)d_in[3];
    const float* Wq_w = (const float*)d_in[4];
    const float* Wq_b = (const float*)d_in[5];
    const float* Wk_w = (const float*)d_in[6];
    const float* Wk_b = (const float*)d_in[7];
    const float* Wv_w = (const float*)d_in[8];
    const float* Wv_b = (const float*)d_in[9];
    const float* E    = (const float*)d_in[10];
    const float* Wo_w = (const float*)d_in[11];
    const float* Wo_b = (const float*)d_in[12];
    float* out = (float*)d_out;

    // ws layout (bytes):
    // G 67108864 | qp/kp/vp/vpT/aob 5x4194304 | mbits 1048576 |
    // Wqb/Wkb/Wvb/Wob 4x524288 | Ebf 1048576       (total ~88 MiB)
    char* ws = (char*)d_ws;
    unsigned short* G   = (unsigned short*)ws;
    unsigned short* qp  = (unsigned short*)(ws + 67108864);
    unsigned short* kp  = qp + 2097152;
    unsigned short* vp  = kp + 2097152;
    unsigned short* vpT = vp + 2097152;
    unsigned short* aob = vpT + 2097152;
    unsigned long long* mbits = (unsigned long long*)(ws + 67108864 + 5 * 4194304);
    unsigned short* Wqb = (unsigned short*)(ws + 67108864 + 5 * 4194304 + 1048576);
    unsigned short* Wkb = Wqb + 262144;
    unsigned short* Wvb = Wkb + 262144;
    unsigned short* Wob = Wvb + 262144;
    unsigned short* Ebf = Wob + 262144;

    dim3 blk(256);
    hipLaunchKernelGGL(prep_kernel, dim3(1536), blk, 0, stream,
                       Wq_w, Wk_w, Wv_w, Wo_w, E, Wqb, Wkb, Wvb, Wob, Ebf);
    hipLaunchKernelGGL(maskpack_kernel, dim3(32768), blk, 0, stream, mask, mbits);
    hipLaunchKernelGGL(gemm_proj, dim3(64, 8, 3), blk, 0, stream,
                       q, k, v, Wqb, Wkb, Wvb, Wq_b, Wk_b, Wv_b, qp, kp, vp);
    hipLaunchKernelGGL(vtrans_kernel, dim3(32, 16), blk, 0, stream, vp, vpT);
    hipLaunchKernelGGL(relg_kernel, dim3(32, 16, 16), blk, 0, stream, qp, Ebf, G);
    hipLaunchKernelGGL(attn_kernel, dim3(64, 16), blk, 0, stream,
                       qp, kp, vpT, mbits, G, aob);
    hipLaunchKernelGGL(gemm_out, dim3(64, 8), blk, 0, stream, aob, Wob, Wo_b, out);
}